// Round 8
// baseline (159.661 us; speedup 1.0000x reference)
//
#include <hip/hip_runtime.h>
#include <hip/hip_fp16.h>
#include <math.h>

#define DFEAT 128
#define RSH 6            // log2(rows per range)
#define RSZ 64           // rows per range
#define NT  512          // threads per block
#define EPB 8192         // edges per hist/scatter chunk
#define EPQ (EPB / NT)   // 16 edges per thread
#define BUF 8192         // gather collect buffer (>= EPB guarantees progress)
#define MAXNR 1024
typedef unsigned long long u64;
typedef unsigned int u32;
typedef unsigned short u16;
#define ENDK 0xFFFFFFFFFFFFFFFFULL

__device__ __forceinline__ void elu_store(const float* x, const float* w,
                                          __half* emb2, int i) {
    float4 xv = ((const float4*)x)[i];
    float4 wv = ((const float4*)w)[i & (DFEAT / 4 - 1)];
    float a, r0, r1, r2, r3;
    a = xv.x * wv.x; r0 = 2.0f * (a > 0.0f ? a : (__expf(a) - 1.0f));
    a = xv.y * wv.y; r1 = 2.0f * (a > 0.0f ? a : (__expf(a) - 1.0f));
    a = xv.z * wv.z; r2 = 2.0f * (a > 0.0f ? a : (__expf(a) - 1.0f));
    a = xv.w * wv.w; r3 = 2.0f * (a > 0.0f ? a : (__expf(a) - 1.0f));
    __half2 h01 = __floats2half2_rn(r0, r1);
    __half2 h23 = __floats2half2_rn(r2, r3);
    uint2 pk;
    pk.x = *(u32*)&h01;
    pk.y = *(u32*)&h23;
    ((uint2*)emb2)[i] = pk;
}

// K1: blocks [0,EB): per-chunk LDS histogram of dst>>RSH, then in-block
// exclusive scan -> loff[c][0..NR], loff[c][NR] = chunk size (coalesced write).
// blocks [EB,..): elu -> emb2 fp16.
__global__ __launch_bounds__(NT) void hist_elu_kernel(
        const float* __restrict__ x, const float* __restrict__ w,
        __half* __restrict__ emb2, int total4,
        const int* __restrict__ dst, int E,
        u32* __restrict__ loff, int EB, int NR) {
    if ((int)blockIdx.x < EB) {
        __shared__ u32 cnt[MAXNR];
        __shared__ u32 sb[NT];
        int tid = threadIdx.x;
        for (int i = tid; i < NR; i += NT) cnt[i] = 0;
        __syncthreads();
        int base = blockIdx.x * EPB;
        for (int q = 0; q < EPQ; ++q) {
            int e = base + tid + q * NT;
            if (e < E) atomicAdd(&cnt[(((u32)dst[e]) >> RSH) & (MAXNR - 1)], 1u);
        }
        __syncthreads();
        // exclusive scan over NR (<= 2*NT) counters: 2 elems/thread
        u32 c0 = (2 * tid     < NR) ? cnt[2 * tid]     : 0u;
        u32 c1 = (2 * tid + 1 < NR) ? cnt[2 * tid + 1] : 0u;
        sb[tid] = c0 + c1;
        __syncthreads();
        for (int d = 1; d < NT; d <<= 1) {
            u32 o = (tid >= d) ? sb[tid - d] : 0u;
            __syncthreads();
            sb[tid] += o;
            __syncthreads();
        }
        u32 excl = sb[tid] - (c0 + c1);
        u32* lrow = loff + (size_t)blockIdx.x * (NR + 1);
        if (2 * tid     < NR) lrow[2 * tid]     = excl;
        if (2 * tid + 1 < NR) lrow[2 * tid + 1] = excl + c0;
        if (tid == 0)         lrow[NR]          = sb[NT - 1];   // chunk total
    } else {
        int idx = (blockIdx.x - EB) * NT + threadIdx.x;
        if (idx < total4) elu_store(x, w, emb2, idx);
    }
}

// K2: LDS-staged chunk sort. Claim within-chunk positions via LDS atomics,
// place pairs in LDS staging, then write the WHOLE chunk back contiguously
// (fully streaming global writes — no random-sector wall).
__global__ __launch_bounds__(NT) void scatter_pairs_kernel(
        const int* __restrict__ src, const int* __restrict__ dst, int E,
        const u32* __restrict__ loff, int EB, int NR,
        u32* __restrict__ pairs) {
    __shared__ u32 off[MAXNR];
    __shared__ u32 stg[EPB];     // 32 KB
    int tid = threadIdx.x;
    int c = blockIdx.x;
    const u32* lrow = loff + (size_t)c * (NR + 1);
    for (int r = tid; r < NR; r += NT) off[r] = lrow[r];
    __syncthreads();
    int base = c * EPB;
    int csz = E - base; if (csz > EPB) csz = EPB;
    for (int q = 0; q < EPQ; ++q) {
        int e = base + tid + q * NT;
        if (e < E) {
            u32 d = (u32)dst[e];
            u32 s = (u32)src[e];
            u32 p = atomicAdd(&off[(d >> RSH) & (MAXNR - 1)], 1u);
            stg[p & (EPB - 1)] = ((d & (RSZ - 1)) << 16) | s;
        }
    }
    __syncthreads();
    for (int i = tid; i < csz; i += NT)
        pairs[base + i] = stg[i];
}

// K3: one block per range. Collect this range's pairs from the EB per-chunk
// segments into LDS (L2/L3-resident reads), counting-sort by local row, then
// row gather with scalar accumulators and 8 clamped loads/batch.
// Multi-pass (degree > BUF) carries partial sums through out[].
__global__ __launch_bounds__(NT) void gather_kernel(
        const __half* __restrict__ emb2, const u32* __restrict__ pairs,
        const u32* __restrict__ loff, int EB, int NR, int E,
        float* __restrict__ out, int N) {
    __shared__ u32 collected[BUF];     // 32 KB
    __shared__ u16 sorted[BUF];        // 16 KB
    __shared__ u32 sb[NT];             // 2 KB
    __shared__ u32 bstart[RSZ + 1];
    __shared__ u32 bplace[RSZ];
    __shared__ u32 sh_ce;
    int tid = threadIdx.x;
    int r = blockIdx.x;
    const int wv = tid >> 6, lane = tid & 63;
    u32 segA = 0, segC = 0;
    if (tid < EB) {
        const u32* lrow = loff + (size_t)tid * (NR + 1);
        segA = lrow[r];
        segC = lrow[r + 1] - segA;
        if (segC > (u32)EPB) segC = 0;   // armor: nonsense count -> drop, no wedge
    }
    bool first = true;
    int cs = 0;
    while (cs < EB) {
        // inclusive scan of segment counts over [cs, EB)
        u32 mycnt = (tid >= cs && tid < EB) ? segC : 0u;
        sb[tid] = mycnt;
        __syncthreads();
        for (int d = 1; d < NT; d <<= 1) {
            u32 o = (tid >= d) ? sb[tid - d] : 0u;
            __syncthreads();
            sb[tid] += o;
            __syncthreads();
        }
        u32 incl = sb[tid];
        u32 base = incl - mycnt;
        if (tid == 0) sh_ce = (u32)(cs + 1);   // segment cs always fits (<=EPB<=BUF)
        __syncthreads();
        bool qok = (tid >= cs && tid < EB && incl <= (u32)BUF);
        if (qok) atomicMax(&sh_ce, (u32)(tid + 1));
        __syncthreads();
        int ce = (int)sh_ce;
        u32 total = (ce > cs) ? sb[ce - 1] : 0u;
        if (total > (u32)BUF) total = (u32)BUF;   // armor
        // copy qualifying segments into collected[]
        if (tid >= cs && tid < ce && segC > 0) {
            u32 gbase = (u32)tid * (u32)EPB + segA;
            for (u32 i = 0; i < segC; ++i)
                collected[(base + i) & (BUF - 1)] = pairs[gbase + i];
        }
        if (tid < RSZ + 1) bstart[tid] = 0;   // counts first
        __syncthreads();
        for (u32 i = tid; i < total; i += NT)
            atomicAdd(&bstart[(collected[i] >> 16) & (RSZ - 1)], 1u);
        __syncthreads();
        if (tid < RSZ) {
            u32 vv = bstart[tid];
            u32 inc = vv;
            for (int d = 1; d < RSZ; d <<= 1) {
                u32 o = __shfl_up(inc, d);
                if (lane >= d) inc += o;
            }
            bstart[tid] = inc - vv;     // exclusive
            bplace[tid] = inc - vv;
            if (tid == RSZ - 1) bstart[RSZ] = inc;
        }
        __syncthreads();
        for (u32 i = tid; i < total; i += NT) {
            u32 pr = collected[i];
            u32 p = atomicAdd(&bplace[(pr >> 16) & (RSZ - 1)], 1u);
            sorted[p & (BUF - 1)] = (u16)(pr & 0xFFFFu);
        }
        __syncthreads();
        // wave wv owns rows [wv*8, wv*8+8)
        for (int rr = 0; rr < 8; ++rr) {
            int row = (wv << 3) + rr;
            int n = (r << RSH) + row;
            int jb = (int)bstart[row], je = (int)bstart[row + 1];
            float ax, ay;
            if (!first && n < N) {
                float2 t = ((const float2*)out)[(size_t)n * (DFEAT / 2) + lane];
                ax = t.x; ay = t.y;
            } else {
                ax = 0.0f; ay = 0.0f;
            }
            for (int j = jb; j < je; j += 8) {
                int last = je - 1;
                int j1 = j + 1 < last ? j + 1 : last;
                int j2 = j + 2 < last ? j + 2 : last;
                int j3 = j + 3 < last ? j + 3 : last;
                int j4 = j + 4 < last ? j + 4 : last;
                int j5 = j + 5 < last ? j + 5 : last;
                int j6 = j + 6 < last ? j + 6 : last;
                int j7 = j + 7 < last ? j + 7 : last;
                u32 q0 = (u32)sorted[j];
                u32 q1 = (u32)sorted[j1];
                u32 q2 = (u32)sorted[j2];
                u32 q3 = (u32)sorted[j3];
                u32 q4 = (u32)sorted[j4];
                u32 q5 = (u32)sorted[j5];
                u32 q6 = (u32)sorted[j6];
                u32 q7 = (u32)sorted[j7];
                u32 h0 = ((const u32*)(emb2 + (size_t)q0 * DFEAT))[lane];
                u32 h1 = ((const u32*)(emb2 + (size_t)q1 * DFEAT))[lane];
                u32 h2 = ((const u32*)(emb2 + (size_t)q2 * DFEAT))[lane];
                u32 h3 = ((const u32*)(emb2 + (size_t)q3 * DFEAT))[lane];
                u32 h4 = ((const u32*)(emb2 + (size_t)q4 * DFEAT))[lane];
                u32 h5 = ((const u32*)(emb2 + (size_t)q5 * DFEAT))[lane];
                u32 h6 = ((const u32*)(emb2 + (size_t)q6 * DFEAT))[lane];
                u32 h7 = ((const u32*)(emb2 + (size_t)q7 * DFEAT))[lane];
                float2 f0 = __half22float2(*(__half2*)&h0);
                ax += f0.x; ay += f0.y;
                if (j + 1 < je) { float2 f = __half22float2(*(__half2*)&h1); ax += f.x; ay += f.y; }
                if (j + 2 < je) { float2 f = __half22float2(*(__half2*)&h2); ax += f.x; ay += f.y; }
                if (j + 3 < je) { float2 f = __half22float2(*(__half2*)&h3); ax += f.x; ay += f.y; }
                if (j + 4 < je) { float2 f = __half22float2(*(__half2*)&h4); ax += f.x; ay += f.y; }
                if (j + 5 < je) { float2 f = __half22float2(*(__half2*)&h5); ax += f.x; ay += f.y; }
                if (j + 6 < je) { float2 f = __half22float2(*(__half2*)&h6); ax += f.x; ay += f.y; }
                if (j + 7 < je) { float2 f = __half22float2(*(__half2*)&h7); ax += f.x; ay += f.y; }
            }
            if (n < N)
                ((float2*)out)[(size_t)n * (DFEAT / 2) + lane] = make_float2(ax, ay);
        }
        __syncthreads();
        first = false;
        cs = ce;
    }
}

// ---------------- fallback paths (unchanged) ----------------

__global__ void bin_elu_ll_kernel(const float* __restrict__ x,
                                  const float* __restrict__ w,
                                  __half* __restrict__ emb2, int total4,
                                  const int* __restrict__ src,
                                  const int* __restrict__ dst, int E,
                                  u64* __restrict__ head,
                                  u64* __restrict__ nxt,
                                  int binBlocks) {
    if ((int)blockIdx.x < binBlocks) {
        int base = blockIdx.x * 1024 + threadIdx.x;
        for (int q = 0; q < 4; ++q) {
            int e = base + q * 256;
            if (e < E) {
                int s = src[e];
                int d = dst[e];
                u64 old = atomicExch(&head[d], ((u64)(u32)s << 32) | (u32)e);
                nxt[e] = old;
            }
        }
    } else {
        int idx = (blockIdx.x - binBlocks) * blockDim.x + threadIdx.x;
        if (idx >= total4) return;
        elu_store(x, w, emb2, idx);
    }
}

__global__ void gather_ll_kernel(const __half* __restrict__ emb2,
                                 const u64* __restrict__ head,
                                 const u64* __restrict__ nxt,
                                 float* __restrict__ out, int N) {
    int wid = (blockIdx.x * blockDim.x + threadIdx.x) >> 6;
    int lane = threadIdx.x & 63;
    int nA = wid * 2;
    int nB = nA + 1;
    if (nA >= N) return;
    bool hasB = (nB < N);
    u64 curA = head[nA];
    u64 curB = hasB ? head[nB] : ENDK;
    float2 accA = make_float2(0.0f, 0.0f);
    float2 accB = make_float2(0.0f, 0.0f);
    while (curA != ENDK || curB != ENDK) {
        bool aA = (curA != ENDK);
        bool aB = (curB != ENDK);
        u64 cA = curA, cB = curB;
        u32 uA = 0, uB = 0;
        if (aA) uA = ((const u32*)(emb2 + ((size_t)(cA >> 32)) * DFEAT))[lane];
        if (aB) uB = ((const u32*)(emb2 + ((size_t)(cB >> 32)) * DFEAT))[lane];
        if (aA) curA = nxt[(u32)cA];
        if (aB) curB = nxt[(u32)cB];
        if (aA) {
            float2 f = __half22float2(*(__half2*)&uA);
            accA.x += f.x; accA.y += f.y;
        }
        if (aB) {
            float2 f = __half22float2(*(__half2*)&uB);
            accB.x += f.x; accB.y += f.y;
        }
    }
    ((float2*)(out + (size_t)nA * DFEAT))[lane] = accA;
    if (hasB) ((float2*)(out + (size_t)nB * DFEAT))[lane] = accB;
}

__global__ void scatter_fused_kernel(const float* __restrict__ x,
                                     const float* __restrict__ w,
                                     const int* __restrict__ src,
                                     const int* __restrict__ dst,
                                     float* __restrict__ out, int E) {
    int t = blockIdx.x * blockDim.x + threadIdx.x;
    int edge = t >> 5;
    int lane = t & 31;
    if (edge >= E) return;
    int s = src[edge];
    int d = dst[edge];
    float4 xv = ((const float4*)(x + (size_t)s * DFEAT))[lane];
    float4 wv = ((const float4*)w)[lane];
    float4 v;
    float a;
    a = xv.x * wv.x; v.x = 2.0f * (a > 0.0f ? a : (__expf(a) - 1.0f));
    a = xv.y * wv.y; v.y = 2.0f * (a > 0.0f ? a : (__expf(a) - 1.0f));
    a = xv.z * wv.z; v.z = 2.0f * (a > 0.0f ? a : (__expf(a) - 1.0f));
    a = xv.w * wv.w; v.w = 2.0f * (a > 0.0f ? a : (__expf(a) - 1.0f));
    float* op = out + (size_t)d * DFEAT + lane * 4;
    unsafeAtomicAdd(op + 0, v.x);
    unsafeAtomicAdd(op + 1, v.y);
    unsafeAtomicAdd(op + 2, v.z);
    unsafeAtomicAdd(op + 3, v.w);
}

extern "C" void kernel_launch(void* const* d_in, const int* in_sizes, int n_in,
                              void* d_out, int out_size, void* d_ws, size_t ws_size,
                              hipStream_t stream) {
    const float* x   = (const float*)d_in[0];   // graph_embedding [N, 128]
    const float* w   = (const float*)d_in[1];   // weight [1, 128]
    const int*   src = (const int*)d_in[3];     // src [E]
    const int*   dst = (const int*)d_in[4];     // dst [E]
    float* out = (float*)d_out;

    const int ND = in_sizes[0];          // N * 128
    const int N  = ND / DFEAT;           // 50000
    const int E  = in_sizes[2];          // 800000

    const int EB = (E + EPB - 1) / EPB;             // chunks (98)
    const int NR = (N + RSZ - 1) >> RSH;            // ranges (782)

    size_t emb_bytes   = ((size_t)ND * sizeof(__half) + 15) & ~(size_t)15;        // 12.8 MB
    size_t loff_bytes  = ((size_t)EB * (NR + 1) * sizeof(u32) + 15) & ~(size_t)15; // ~307 KB
    size_t pairs_bytes = ((size_t)E * sizeof(u32) + 15) & ~(size_t)15;            // 3.2 MB
    size_t total_new = emb_bytes + loff_bytes + pairs_bytes;

    size_t head64_bytes = ((size_t)N * sizeof(u64) + 15) & ~(size_t)15;
    size_t nxt64_bytes  = ((size_t)E * sizeof(u64) + 15) & ~(size_t)15;
    size_t total_old = emb_bytes + head64_bytes + nxt64_bytes;

    int total4 = ND / 4;

    if (ws_size >= total_new && N <= 65536 && NR <= MAXNR && EB <= NT) {
        char* p = (char*)d_ws;
        __half* emb2  = (__half*)p;  p += emb_bytes;
        u32*    loff  = (u32*)p;     p += loff_bytes;
        u32*    pairs = (u32*)p;

        int eluBlocks = (total4 + NT - 1) / NT;
        hist_elu_kernel<<<EB + eluBlocks, NT, 0, stream>>>(
            x, w, emb2, total4, dst, E, loff, EB, NR);

        scatter_pairs_kernel<<<EB, NT, 0, stream>>>(
            src, dst, E, loff, EB, NR, pairs);

        gather_kernel<<<NR, NT, 0, stream>>>(
            emb2, pairs, loff, EB, NR, E, out, N);
    } else if (ws_size >= total_old) {
        char* p = (char*)d_ws;
        __half* emb2 = (__half*)p;  p += emb_bytes;
        u64*    head = (u64*)p;     p += head64_bytes;
        u64*    nxt  = (u64*)p;

        hipMemsetAsync(head, 0xFF, (size_t)N * sizeof(u64), stream);

        int eluBlocks256 = (total4 + 255) / 256;
        int binBlocks = (E + 1023) / 1024;
        bin_elu_ll_kernel<<<binBlocks + eluBlocks256, 256, 0, stream>>>(
            x, w, emb2, total4, src, dst, E, head, nxt, binBlocks);

        long long waves = (N + 1) / 2;
        long long thr = waves * 64;
        gather_ll_kernel<<<(int)((thr + 255) / 256), 256, 0, stream>>>(
            emb2, head, nxt, out, N);
    } else {
        hipMemsetAsync(d_out, 0, (size_t)out_size * sizeof(float), stream);
        long long threads = (long long)E * 32;
        scatter_fused_kernel<<<(int)((threads + 255) / 256), 256, 0, stream>>>(x, w, src, dst, out, E);
    }
}

// Round 9
// 146.818 us; speedup vs baseline: 1.0875x; 1.0875x over previous
//
#include <hip/hip_runtime.h>
#include <hip/hip_fp16.h>
#include <math.h>

#define DFEAT 128
#define RSH 5            // log2(rows per range) -- 32-row ranges: 2x grid for gather
#define RSZ 32           // rows per range
#define NT  512          // threads per block
#define EPB 8192         // edges per hist/scatter block
#define EPQ (EPB / NT)   // 16 edges per thread
#define CHUNK 2048       // pairs per sort chunk in gather
#define MAXNR 2048
#define TILESH 9         // scan tile = 512 elements
#define TILE (1 << TILESH)
typedef unsigned long long u64;
typedef unsigned int u32;
typedef unsigned short u16;
#define ENDK 0xFFFFFFFFFFFFFFFFULL

__device__ __forceinline__ void elu_store(const float* x, const float* w,
                                          __half* emb2, int i) {
    float4 xv = ((const float4*)x)[i];
    float4 wv = ((const float4*)w)[i & (DFEAT / 4 - 1)];
    float a, r0, r1, r2, r3;
    a = xv.x * wv.x; r0 = 2.0f * (a > 0.0f ? a : (__expf(a) - 1.0f));
    a = xv.y * wv.y; r1 = 2.0f * (a > 0.0f ? a : (__expf(a) - 1.0f));
    a = xv.z * wv.z; r2 = 2.0f * (a > 0.0f ? a : (__expf(a) - 1.0f));
    a = xv.w * wv.w; r3 = 2.0f * (a > 0.0f ? a : (__expf(a) - 1.0f));
    __half2 h01 = __floats2half2_rn(r0, r1);
    __half2 h23 = __floats2half2_rn(r2, r3);
    uint2 pk;
    pk.x = *(u32*)&h01;
    pk.y = *(u32*)&h23;
    ((uint2*)emb2)[i] = pk;
}

// Redundant per-block exclusive scan of tsum[0..nT) into ts[512] (LDS).
__device__ __forceinline__ void scan_tsum_lds(const u32* tsum, u32* ts, int nT) {
    int tid = threadIdx.x;
    u32 v = (tid < nT) ? tsum[tid] : 0u;
    ts[tid] = v;
    __syncthreads();
    for (int d = 1; d < NT; d <<= 1) {
        u32 o = (tid >= d) ? ts[tid - d] : 0u;
        __syncthreads();
        ts[tid] += o;
        __syncthreads();
    }
    u32 incl = ts[tid];
    __syncthreads();
    ts[tid] = incl - v;          // exclusive
    __syncthreads();
}

// K1: blocks [0,EB): LDS histogram of dst>>RSH -> ghist[r][block].
//     blocks [EB,..): elu -> emb2 fp16.
__global__ __launch_bounds__(NT) void hist_elu_kernel(
        const float* __restrict__ x, const float* __restrict__ w,
        __half* __restrict__ emb2, int total4,
        const int* __restrict__ dst, int E,
        u32* __restrict__ ghist, int EB, int NR) {
    if ((int)blockIdx.x < EB) {
        __shared__ u32 hist[MAXNR];
        int tid = threadIdx.x;
        for (int i = tid; i < NR; i += NT) hist[i] = 0;
        __syncthreads();
        int base = blockIdx.x * EPB;
        for (int q = 0; q < EPQ; ++q) {
            int e = base + tid + q * NT;
            if (e < E) atomicAdd(&hist[(((u32)dst[e]) >> RSH) & (MAXNR - 1)], 1u);
        }
        __syncthreads();
        for (int r = tid; r < NR; r += NT)
            ghist[(size_t)r * EB + blockIdx.x] = hist[r];
    } else {
        int idx = (blockIdx.x - EB) * NT + threadIdx.x;
        if (idx < total4) elu_store(x, w, emb2, idx);
    }
}

// K2: per-tile local-exclusive scan; tsum[tile] = tile total.
__global__ __launch_bounds__(NT) void scan_tile_kernel(
        u32* __restrict__ g, u32* __restrict__ tsum, int M) {
    __shared__ u32 sc[NT];
    int tid = threadIdx.x;
    int i = (blockIdx.x << TILESH) + tid;
    u32 v = (i < M) ? g[i] : 0u;
    sc[tid] = v;
    __syncthreads();
    for (int d = 1; d < NT; d <<= 1) {
        u32 o = (tid >= d) ? sc[tid - d] : 0u;
        __syncthreads();
        sc[tid] += o;
        __syncthreads();
    }
    if (i < M) g[i] = sc[tid] - v;
    if (tid == NT - 1) tsum[blockIdx.x] = sc[NT - 1];
}

// K3: scatter pairs into per-(range,block) contiguous runs; LDS atomics only.
__global__ __launch_bounds__(NT) void scatter_pairs_kernel(
        const int* __restrict__ src, const int* __restrict__ dst, int E,
        const u32* __restrict__ ghist, const u32* __restrict__ tsum,
        int EB, int NR, int nT, u32* __restrict__ pairs) {
    __shared__ u32 ts[NT];
    __shared__ u32 off[MAXNR];
    int tid = threadIdx.x;
    scan_tsum_lds(tsum, ts, nT);
    for (int r = tid; r < NR; r += NT) {
        u32 idx = (u32)r * EB + blockIdx.x;
        off[r] = ghist[idx] + ts[idx >> TILESH];
    }
    __syncthreads();
    int base = blockIdx.x * EPB;
    for (int q = 0; q < EPQ; ++q) {
        int e = base + tid + q * NT;
        if (e < E) {
            u32 d = (u32)dst[e];
            u32 s = (u32)src[e];
            u32 p = atomicAdd(&off[(d >> RSH) & (MAXNR - 1)], 1u);
            if (p < (u32)E) pairs[p] = ((d & (RSZ - 1)) << 16) | s;
        }
    }
}

// K4: one block per 32-row range (NR=1563 blocks -> ~6 blocks/CU queued, wave
// slots saturated). LDS counting-sort by local row, then row gather with
// scalar accumulators and 8 clamped loads per batch. s0/s1 clamped (armor).
__global__ __launch_bounds__(NT) void gather_sort_kernel(
        const __half* __restrict__ emb2, const u32* __restrict__ pairs,
        const u32* __restrict__ ghist, const u32* __restrict__ tsum,
        int EB, int NR, int nT, int E,
        float* __restrict__ out, int N) {
    __shared__ u32 ts[NT];
    __shared__ u16 sorted[CHUNK];
    __shared__ u32 bcnt[RSZ + 1];
    __shared__ u32 bstart[RSZ + 1];
    int tid = threadIdx.x;
    scan_tsum_lds(tsum, ts, nT);
    int r = blockIdx.x;
    u32 ia = (u32)r * (u32)EB;
    u32 s0 = ghist[ia] + ts[ia >> TILESH];
    u32 s1 = (r + 1 < NR) ? (ghist[ia + EB] + ts[(ia + EB) >> TILESH]) : (u32)E;
    if (s0 > (u32)E) s0 = (u32)E;
    if (s1 > (u32)E) s1 = (u32)E;
    if (s1 < s0) s1 = s0;
    __syncthreads();
    const int wv = tid >> 6;
    const int lane = tid & 63;
    u32 pos = s0;
    do {
        int csz = 0;
        if (s1 > pos) {
            u32 rem = s1 - pos;
            csz = rem < (u32)CHUNK ? (int)rem : CHUNK;
        }
        if (tid < RSZ + 1) bcnt[tid] = 0;
        __syncthreads();
        u32 p0 = 0, p1 = 0, p2 = 0, p3 = 0;
        int  r0 = -1, r1 = -1, r2 = -1, r3 = -1;
        {
            int e0 = tid, e1 = tid + NT, e2 = tid + 2 * NT, e3 = tid + 3 * NT;
            if (e0 < csz) { p0 = pairs[pos + e0]; r0 = (int)(p0 >> 16); }
            if (e1 < csz) { p1 = pairs[pos + e1]; r1 = (int)(p1 >> 16); }
            if (e2 < csz) { p2 = pairs[pos + e2]; r2 = (int)(p2 >> 16); }
            if (e3 < csz) { p3 = pairs[pos + e3]; r3 = (int)(p3 >> 16); }
            if (r0 >= 0) atomicAdd(&bcnt[r0 & (RSZ - 1)], 1u);
            if (r1 >= 0) atomicAdd(&bcnt[r1 & (RSZ - 1)], 1u);
            if (r2 >= 0) atomicAdd(&bcnt[r2 & (RSZ - 1)], 1u);
            if (r3 >= 0) atomicAdd(&bcnt[r3 & (RSZ - 1)], 1u);
        }
        __syncthreads();
        if (tid < RSZ) {
            u32 vv = bcnt[tid];
            u32 inc = vv;
            for (int d = 1; d < RSZ; d <<= 1) {
                u32 o = __shfl_up(inc, d);
                if (lane >= d) inc += o;
            }
            bstart[tid] = inc - vv;
            bcnt[tid]   = inc - vv;
            if (tid == RSZ - 1) bstart[RSZ] = inc;
        }
        __syncthreads();
        if (r0 >= 0) { u32 p = atomicAdd(&bcnt[r0 & (RSZ - 1)], 1u); sorted[p & (CHUNK - 1)] = (u16)(p0 & 0xFFFFu); }
        if (r1 >= 0) { u32 p = atomicAdd(&bcnt[r1 & (RSZ - 1)], 1u); sorted[p & (CHUNK - 1)] = (u16)(p1 & 0xFFFFu); }
        if (r2 >= 0) { u32 p = atomicAdd(&bcnt[r2 & (RSZ - 1)], 1u); sorted[p & (CHUNK - 1)] = (u16)(p2 & 0xFFFFu); }
        if (r3 >= 0) { u32 p = atomicAdd(&bcnt[r3 & (RSZ - 1)], 1u); sorted[p & (CHUNK - 1)] = (u16)(p3 & 0xFFFFu); }
        __syncthreads();
        // wave wv owns rows [wv*4, wv*4+4)
        for (int rr = 0; rr < 4; ++rr) {
            int row = (wv << 2) + rr;
            int n = (r << RSH) + row;
            int jb = (int)bstart[row], je = (int)bstart[row + 1];
            float ax, ay;
            if (pos != s0 && n < N) {
                float2 t = ((const float2*)out)[(size_t)n * (DFEAT / 2) + lane];
                ax = t.x; ay = t.y;
            } else {
                ax = 0.0f; ay = 0.0f;
            }
            for (int j = jb; j < je; j += 8) {
                int last = je - 1;
                int j1 = j + 1 < last ? j + 1 : last;
                int j2 = j + 2 < last ? j + 2 : last;
                int j3 = j + 3 < last ? j + 3 : last;
                int j4 = j + 4 < last ? j + 4 : last;
                int j5 = j + 5 < last ? j + 5 : last;
                int j6 = j + 6 < last ? j + 6 : last;
                int j7 = j + 7 < last ? j + 7 : last;
                u32 q0 = (u32)sorted[j];
                u32 q1 = (u32)sorted[j1];
                u32 q2 = (u32)sorted[j2];
                u32 q3 = (u32)sorted[j3];
                u32 q4 = (u32)sorted[j4];
                u32 q5 = (u32)sorted[j5];
                u32 q6 = (u32)sorted[j6];
                u32 q7 = (u32)sorted[j7];
                u32 h0 = ((const u32*)(emb2 + (size_t)q0 * DFEAT))[lane];
                u32 h1 = ((const u32*)(emb2 + (size_t)q1 * DFEAT))[lane];
                u32 h2 = ((const u32*)(emb2 + (size_t)q2 * DFEAT))[lane];
                u32 h3 = ((const u32*)(emb2 + (size_t)q3 * DFEAT))[lane];
                u32 h4 = ((const u32*)(emb2 + (size_t)q4 * DFEAT))[lane];
                u32 h5 = ((const u32*)(emb2 + (size_t)q5 * DFEAT))[lane];
                u32 h6 = ((const u32*)(emb2 + (size_t)q6 * DFEAT))[lane];
                u32 h7 = ((const u32*)(emb2 + (size_t)q7 * DFEAT))[lane];
                float2 f0 = __half22float2(*(__half2*)&h0);
                ax += f0.x; ay += f0.y;
                if (j + 1 < je) { float2 f = __half22float2(*(__half2*)&h1); ax += f.x; ay += f.y; }
                if (j + 2 < je) { float2 f = __half22float2(*(__half2*)&h2); ax += f.x; ay += f.y; }
                if (j + 3 < je) { float2 f = __half22float2(*(__half2*)&h3); ax += f.x; ay += f.y; }
                if (j + 4 < je) { float2 f = __half22float2(*(__half2*)&h4); ax += f.x; ay += f.y; }
                if (j + 5 < je) { float2 f = __half22float2(*(__half2*)&h5); ax += f.x; ay += f.y; }
                if (j + 6 < je) { float2 f = __half22float2(*(__half2*)&h6); ax += f.x; ay += f.y; }
                if (j + 7 < je) { float2 f = __half22float2(*(__half2*)&h7); ax += f.x; ay += f.y; }
            }
            if (n < N)
                ((float2*)out)[(size_t)n * (DFEAT / 2) + lane] = make_float2(ax, ay);
        }
        __syncthreads();
        pos += CHUNK;
    } while (pos < s1);
}

// ---------------- fallback paths (unchanged) ----------------

__global__ void bin_elu_ll_kernel(const float* __restrict__ x,
                                  const float* __restrict__ w,
                                  __half* __restrict__ emb2, int total4,
                                  const int* __restrict__ src,
                                  const int* __restrict__ dst, int E,
                                  u64* __restrict__ head,
                                  u64* __restrict__ nxt,
                                  int binBlocks) {
    if ((int)blockIdx.x < binBlocks) {
        int base = blockIdx.x * 1024 + threadIdx.x;
        for (int q = 0; q < 4; ++q) {
            int e = base + q * 256;
            if (e < E) {
                int s = src[e];
                int d = dst[e];
                u64 old = atomicExch(&head[d], ((u64)(u32)s << 32) | (u32)e);
                nxt[e] = old;
            }
        }
    } else {
        int idx = (blockIdx.x - binBlocks) * blockDim.x + threadIdx.x;
        if (idx >= total4) return;
        elu_store(x, w, emb2, idx);
    }
}

__global__ void gather_ll_kernel(const __half* __restrict__ emb2,
                                 const u64* __restrict__ head,
                                 const u64* __restrict__ nxt,
                                 float* __restrict__ out, int N) {
    int wid = (blockIdx.x * blockDim.x + threadIdx.x) >> 6;
    int lane = threadIdx.x & 63;
    int nA = wid * 2;
    int nB = nA + 1;
    if (nA >= N) return;
    bool hasB = (nB < N);
    u64 curA = head[nA];
    u64 curB = hasB ? head[nB] : ENDK;
    float2 accA = make_float2(0.0f, 0.0f);
    float2 accB = make_float2(0.0f, 0.0f);
    while (curA != ENDK || curB != ENDK) {
        bool aA = (curA != ENDK);
        bool aB = (curB != ENDK);
        u64 cA = curA, cB = curB;
        u32 uA = 0, uB = 0;
        if (aA) uA = ((const u32*)(emb2 + ((size_t)(cA >> 32)) * DFEAT))[lane];
        if (aB) uB = ((const u32*)(emb2 + ((size_t)(cB >> 32)) * DFEAT))[lane];
        if (aA) curA = nxt[(u32)cA];
        if (aB) curB = nxt[(u32)cB];
        if (aA) {
            float2 f = __half22float2(*(__half2*)&uA);
            accA.x += f.x; accA.y += f.y;
        }
        if (aB) {
            float2 f = __half22float2(*(__half2*)&uB);
            accB.x += f.x; accB.y += f.y;
        }
    }
    ((float2*)(out + (size_t)nA * DFEAT))[lane] = accA;
    if (hasB) ((float2*)(out + (size_t)nB * DFEAT))[lane] = accB;
}

__global__ void scatter_fused_kernel(const float* __restrict__ x,
                                     const float* __restrict__ w,
                                     const int* __restrict__ src,
                                     const int* __restrict__ dst,
                                     float* __restrict__ out, int E) {
    int t = blockIdx.x * blockDim.x + threadIdx.x;
    int edge = t >> 5;
    int lane = t & 31;
    if (edge >= E) return;
    int s = src[edge];
    int d = dst[edge];
    float4 xv = ((const float4*)(x + (size_t)s * DFEAT))[lane];
    float4 wv = ((const float4*)w)[lane];
    float4 v;
    float a;
    a = xv.x * wv.x; v.x = 2.0f * (a > 0.0f ? a : (__expf(a) - 1.0f));
    a = xv.y * wv.y; v.y = 2.0f * (a > 0.0f ? a : (__expf(a) - 1.0f));
    a = xv.z * wv.z; v.z = 2.0f * (a > 0.0f ? a : (__expf(a) - 1.0f));
    a = xv.w * wv.w; v.w = 2.0f * (a > 0.0f ? a : (__expf(a) - 1.0f));
    float* op = out + (size_t)d * DFEAT + lane * 4;
    unsafeAtomicAdd(op + 0, v.x);
    unsafeAtomicAdd(op + 1, v.y);
    unsafeAtomicAdd(op + 2, v.z);
    unsafeAtomicAdd(op + 3, v.w);
}

extern "C" void kernel_launch(void* const* d_in, const int* in_sizes, int n_in,
                              void* d_out, int out_size, void* d_ws, size_t ws_size,
                              hipStream_t stream) {
    const float* x   = (const float*)d_in[0];   // graph_embedding [N, 128]
    const float* w   = (const float*)d_in[1];   // weight [1, 128]
    const int*   src = (const int*)d_in[3];     // src [E]
    const int*   dst = (const int*)d_in[4];     // dst [E]
    float* out = (float*)d_out;

    const int ND = in_sizes[0];          // N * 128
    const int N  = ND / DFEAT;           // 50000
    const int E  = in_sizes[2];          // 800000

    const int EB = (E + EPB - 1) / EPB;             // hist/scatter blocks (98)
    const int NR = (N + RSZ - 1) >> RSH;            // ranges (1563)
    const int M  = NR * EB;                         // ghist entries (~153K)
    const int nT = (M + TILE - 1) >> TILESH;        // scan tiles (~300)

    size_t emb_bytes   = ((size_t)ND * sizeof(__half) + 15) & ~(size_t)15;   // 12.8 MB
    size_t ghist_bytes = ((size_t)M * sizeof(u32) + 15) & ~(size_t)15;       // ~0.6 MB
    size_t tsum_bytes  = ((size_t)NT * sizeof(u32) + 15) & ~(size_t)15;      // 2 KB
    size_t pairs_bytes = ((size_t)E * sizeof(u32) + 15) & ~(size_t)15;       // 3.2 MB
    size_t total_new = emb_bytes + ghist_bytes + tsum_bytes + pairs_bytes;

    size_t head64_bytes = ((size_t)N * sizeof(u64) + 15) & ~(size_t)15;
    size_t nxt64_bytes  = ((size_t)E * sizeof(u64) + 15) & ~(size_t)15;
    size_t total_old = emb_bytes + head64_bytes + nxt64_bytes;

    int total4 = ND / 4;

    if (ws_size >= total_new && N <= 65536 && NR <= MAXNR && nT <= NT) {
        char* p = (char*)d_ws;
        __half* emb2  = (__half*)p;  p += emb_bytes;
        u32*    ghist = (u32*)p;     p += ghist_bytes;
        u32*    tsum  = (u32*)p;     p += tsum_bytes;
        u32*    pairs = (u32*)p;

        int eluBlocks = (total4 + NT - 1) / NT;
        hist_elu_kernel<<<EB + eluBlocks, NT, 0, stream>>>(
            x, w, emb2, total4, dst, E, ghist, EB, NR);

        scan_tile_kernel<<<nT, NT, 0, stream>>>(ghist, tsum, M);

        scatter_pairs_kernel<<<EB, NT, 0, stream>>>(
            src, dst, E, ghist, tsum, EB, NR, nT, pairs);

        gather_sort_kernel<<<NR, NT, 0, stream>>>(
            emb2, pairs, ghist, tsum, EB, NR, nT, E, out, N);
    } else if (ws_size >= total_old) {
        char* p = (char*)d_ws;
        __half* emb2 = (__half*)p;  p += emb_bytes;
        u64*    head = (u64*)p;     p += head64_bytes;
        u64*    nxt  = (u64*)p;

        hipMemsetAsync(head, 0xFF, (size_t)N * sizeof(u64), stream);

        int eluBlocks256 = (total4 + 255) / 256;
        int binBlocks = (E + 1023) / 1024;
        bin_elu_ll_kernel<<<binBlocks + eluBlocks256, 256, 0, stream>>>(
            x, w, emb2, total4, src, dst, E, head, nxt, binBlocks);

        long long waves = (N + 1) / 2;
        long long thr = waves * 64;
        gather_ll_kernel<<<(int)((thr + 255) / 256), 256, 0, stream>>>(
            emb2, head, nxt, out, N);
    } else {
        hipMemsetAsync(d_out, 0, (size_t)out_size * sizeof(float), stream);
        long long threads = (long long)E * 32;
        scatter_fused_kernel<<<(int)((threads + 255) / 256), 256, 0, stream>>>(x, w, src, dst, out, E);
    }
}